// Round 5
// baseline (4132.261 us; speedup 1.0000x reference)
//
#include <hip/hip_runtime.h>

// Problem dims (fixed)
constexpr int T  = 512;
constexpr int NB = 64;    // batch
constexpr int NI = 128;   // input
constexpr int NH = 512;   // hidden
constexpr int NO = 64;    // output

constexpr float ALPHA = 0.2f;
constexpr float NSC   = 0.063245553203367586f; // 0.1*sqrt(2*ALPHA)

// ---------------------------------------------------------------------------
// Generic fp32 GEMM: C[M,N] = A[M,K] @ B[N,K]^T + bias[N]   (R3-proven)
__global__ __launch_bounds__(256) void k_gemm_nt_bias(
    const float* __restrict__ A, const float* __restrict__ Bm,
    const float* __restrict__ bias, float* __restrict__ C,
    int M, int N, int K)
{
    __shared__ __align__(16) float As[32][68];
    __shared__ __align__(16) float Bs[32][68];
    const int tid = threadIdx.x;
    const int tx = tid & 15, ty = tid >> 4;
    const long row0 = (long)blockIdx.x * 64;
    const long col0 = (long)blockIdx.y * 64;
    const int lr = tid >> 3;
    const int lq = tid & 7;

    float acc[4][4] = {};

    for (int kt = 0; kt < K; kt += 32) {
        #pragma unroll
        for (int hh = 0; hh < 2; ++hh) {
            const int r = lr + hh * 32;
            const float4 va = *(const float4*)&A[(size_t)(row0 + r) * K + kt + lq * 4];
            As[lq*4+0][r] = va.x; As[lq*4+1][r] = va.y;
            As[lq*4+2][r] = va.z; As[lq*4+3][r] = va.w;
            const float4 vb = *(const float4*)&Bm[(size_t)(col0 + r) * K + kt + lq * 4];
            Bs[lq*4+0][r] = vb.x; Bs[lq*4+1][r] = vb.y;
            Bs[lq*4+2][r] = vb.z; Bs[lq*4+3][r] = vb.w;
        }
        __syncthreads();
        #pragma unroll
        for (int kk = 0; kk < 32; ++kk) {
            const float4 a4 = *(const float4*)&As[kk][ty * 4];
            const float4 b4 = *(const float4*)&Bs[kk][tx * 4];
            const float a[4] = {a4.x, a4.y, a4.z, a4.w};
            const float b[4] = {b4.x, b4.y, b4.z, b4.w};
            #pragma unroll
            for (int i = 0; i < 4; ++i)
                #pragma unroll
                for (int j = 0; j < 4; ++j)
                    acc[i][j] += a[i] * b[j];
        }
        __syncthreads();
    }

    #pragma unroll
    for (int i = 0; i < 4; ++i) {
        const long r = row0 + ty * 4 + i;
        const int  cc = (int)col0 + tx * 4;
        float4 ov;
        ov.x = acc[i][0] + bias[cc + 0];
        ov.y = acc[i][1] + bias[cc + 1];
        ov.z = acc[i][2] + bias[cc + 2];
        ov.w = acc[i][3] + bias[cc + 3];
        *(float4*)&C[(size_t)r * N + cc] = ov;
    }
}

// ---------------------------------------------------------------------------
// u32 exchange word (R3-PROVEN primitive): [31:16]=bf16(h), [15:0]=tag.
// Published with atomic exchange, polled with atomic fetch_or(0) — both
// RELAXED + AGENT-scope RMWs executing at the device coherence point
// (cross-XCD-safe, no cache-maintenance instructions in the loop).
__device__ __forceinline__ uint32_t pack_h(float h, uint32_t tag) {
    uint32_t u = __float_as_uint(h);
    uint32_t r = (u + 0x7FFFu + ((u >> 16) & 1u)) & 0xFFFF0000u;  // RNE to bf16
    return r | (tag & 0xFFFFu);
}

// ---------------------------------------------------------------------------
// Recurrent kernel, software-pipelined across 4 batches per group.
//  64 WGs = 16 groups x 4 members. Group g owns batches {4g..4g+3};
//  member m owns hidden cols [128m, 128m+128) (W slice in regs/AGPRs,
//  128 floats/lane — same as R3). bid = m*16+g -> members share bid%8.
// Iteration t has 4 phases (B=0..3), each:
//   dot(batch B, h_B(t)) [all 512 thr] ; barrier ;
//   { tid<128:  epilogue(batch B): reduce partials, h_B(t+1) own cols,
//               publish tag t+1, write rnn[t], prefetch xin/noise(t+1)
//   | tid>=128: poll batch (B+1)%4's peer words, version v
//               (v = t for B=0..2, t+1 for B=3; skipped while v==0) } ; barrier.
// Publish(b,v) -> gather(b,v) gap = 3 phases (~1.5us) >= RTT -> sync hidden.
// Overwrite safety (2 slots, parity v&1): member m's publish(x,v+2) at phase
//  q is preceded by m's gather at q-1 of words published at q-4, whose
//  publishers had completed phase q-5 (end-barrier) = the phase in which ALL
//  peers read (x,v). So no word is overwritten before all its readers passed.
// Hang-proofing: LAUNCH-GLOBAL spin budget 2^16/thread + sticky alive ->
//  a total visibility failure costs ~5 ms/launch (fast wrong answer),
//  never a dead container.
__global__ __launch_bounds__(512, 2) void k_rnn(
    const float* __restrict__ W_rec,   // [H][H]
    const float* __restrict__ noise,   // [T][B][H]
    float* __restrict__ rnn,           // [T][B][H]: xin+b_rec in, h out
    uint32_t* __restrict__ ex)         // [2][B][H] tagged words
{
    const int bid = blockIdx.x;
    const int g = bid & 15;        // group 0..15
    const int m = bid >> 4;        // member 0..3
    const int tid = threadIdx.x;
    const int jl  = tid & 127;     // col within slice (dot)
    const int kc  = tid >> 7;      // k-chunk 0..3 (128 wide)

    __shared__ __align__(16) float h[4][NH];    // h state, one row per batch
    __shared__ __align__(16) float pr[4][128];  // per-kc partials (reused)

    // ---- W slice (one-time): row m*128+jl, k in [128kc, 128kc+128) ----
    float4 wreg[32];
    {
        const float* wp = W_rec + (size_t)(m * 128 + jl) * NH + kc * 128;
        #pragma unroll
        for (int i = 0; i < 32; ++i) wreg[i] = *(const float4*)(wp + i * 4);
    }

    const int gc = m * 128 + tid;            // epilogue col (tid<128)

    // poller mapping (tid>=128): one u32 word of the gather batch
    const int q   = tid - 128;               // 0..383
    const int pp  = q >> 7;                  // 0..2
    const int pm  = pp + (pp >= m ? 1 : 0);  // peer member
    const int pcol = pm * 128 + (q & 127);

    // zero h state (tid covers NH=512)
    #pragma unroll
    for (int x = 0; x < 4; ++x) h[x][tid] = 0.f;

    // prefetch t=0 xin(+b_rec) and noise for all 4 batches (own col)
    float xin0 = 0.f, xin1 = 0.f, xin2 = 0.f, xin3 = 0.f;
    float noi0 = 0.f, noi1 = 0.f, noi2 = 0.f, noi3 = 0.f;
    if (tid < 128) {
        xin0 = rnn[(size_t)(g * 4 + 0) * NH + gc];
        xin1 = rnn[(size_t)(g * 4 + 1) * NH + gc];
        xin2 = rnn[(size_t)(g * 4 + 2) * NH + gc];
        xin3 = rnn[(size_t)(g * 4 + 3) * NH + gc];
        noi0 = noise[(size_t)(g * 4 + 0) * NH + gc];
        noi1 = noise[(size_t)(g * 4 + 1) * NH + gc];
        noi2 = noise[(size_t)(g * 4 + 2) * NH + gc];
        noi3 = noise[(size_t)(g * 4 + 3) * NH + gc];
    }
    __syncthreads();

    int alive  = 1;
    int budget = 1 << 16;   // launch-global spin budget (hang-proof)

#define RNN_PHASE(B, XIN, NOI)                                                  \
    {                                                                           \
        /* ---- dot(batch B): lane's 128-k chunk, broadcast LDS reads ---- */   \
        float ax = 0.f, ay = 0.f, az = 0.f, aw = 0.f;                           \
        {                                                                       \
            const float* hp = &h[B][kc * 128];                                  \
            _Pragma("unroll")                                                   \
            for (int i = 0; i < 32; ++i) {                                      \
                const float4 u = *(const float4*)(hp + i * 4);                  \
                ax += wreg[i].x * u.x;  ay += wreg[i].y * u.y;                  \
                az += wreg[i].z * u.z;  aw += wreg[i].w * u.w;                  \
            }                                                                   \
        }                                                                       \
        pr[kc][jl] = (ax + ay) + (az + aw);                                     \
        __syncthreads();                                                        \
        const uint32_t want = ((B) == 3) ? (uint32_t)(t + 1) : (uint32_t)t;     \
        if (tid < 128) {                                                        \
            const float sum = pr[0][tid] + pr[1][tid] + pr[2][tid] + pr[3][tid];\
            const float hn  = fmaxf(XIN + sum, 0.f);  /* b_rec in xin */        \
            const float nw  = (1.f - ALPHA) * h[B][gc] + ALPHA * hn + NSC * NOI;\
            h[B][gc] = nw;                                                      \
            (void)__hip_atomic_exchange(                                        \
                &ex[(((t + 1) & 1) * NB + (g * 4 + (B))) * NH + gc],            \
                pack_h(nw, (uint32_t)(t + 1)),                                  \
                __ATOMIC_RELAXED, __HIP_MEMORY_SCOPE_AGENT);                    \
            rnn[((size_t)t * NB + (g * 4 + (B))) * NH + gc] = nw;               \
            const int tn = (t + 1 < T) ? (t + 1) : t;                           \
            XIN = rnn[((size_t)tn * NB + (g * 4 + (B))) * NH + gc];             \
            NOI = noise[((size_t)tn * NB + (g * 4 + (B))) * NH + gc];           \
        } else if (want >= 1) {                                                 \
            const int gx = ((B) + 1) & 3;                                       \
            uint32_t* wp2 = &ex[((want & 1) * NB + (g * 4 + gx)) * NH + pcol];  \
            uint32_t w;                                                         \
            if (alive) {                                                        \
                for (;;) {                                                      \
                    w = __hip_atomic_fetch_or(wp2, 0u,                          \
                            __ATOMIC_RELAXED, __HIP_MEMORY_SCOPE_AGENT);        \
                    if ((w & 0xFFFFu) == (want & 0xFFFFu)) break;               \
                    __builtin_amdgcn_s_sleep(1);                                \
                    if (--budget < 0) { alive = 0; break; }                     \
                }                                                               \
            } else {                                                            \
                w = __hip_atomic_fetch_or(wp2, 0u,                              \
                        __ATOMIC_RELAXED, __HIP_MEMORY_SCOPE_AGENT);            \
            }                                                                   \
            h[gx][pcol] = __uint_as_float(w & 0xFFFF0000u);                     \
        }                                                                       \
        __syncthreads();                                                        \
    }

    for (int t = 0; t < T; ++t) {
        RNN_PHASE(0, xin0, noi0)
        RNN_PHASE(1, xin1, noi1)
        RNN_PHASE(2, xin2, noi2)
        RNN_PHASE(3, xin3, noi3)
    }
#undef RNN_PHASE
}

// ---------------------------------------------------------------------------
extern "C" void kernel_launch(void* const* d_in, const int* in_sizes, int n_in,
                              void* d_out, int out_size, void* d_ws, size_t ws_size,
                              hipStream_t stream)
{
    (void)in_sizes; (void)n_in; (void)out_size; (void)ws_size;
    const float* x     = (const float*)d_in[0];
    const float* noise = (const float*)d_in[1];
    const float* W_in  = (const float*)d_in[2];
    const float* W_rec = (const float*)d_in[3];
    const float* b_rec = (const float*)d_in[4];
    const float* W_out = (const float*)d_in[5];
    const float* b_out = (const float*)d_in[6];

    float* out = (float*)d_out;                       // [T*B][O]
    float* rnn = out + (size_t)T * NB * NO;           // [T*B][H] (second output)

    uint32_t* ex = (uint32_t*)d_ws;                   // [2][B][H] = 256 KB

    // clear exchange tags (replay-deterministic; tag 0 never polled-for)
    hipMemsetAsync(ex, 0, (size_t)2 * NB * NH * sizeof(uint32_t), stream);

    // xin = x @ W_in^T + b_rec  -> written into rnn region (in-place consumed)
    hipLaunchKernelGGL(k_gemm_nt_bias, dim3((T * NB) / 64, NH / 64), dim3(256), 0, stream,
                       x, W_in, b_rec, rnn, T * NB, NH, NI);

    // sequential recurrence: 64 WGs, 4-batch pipelined, u32 RMW sync
    hipLaunchKernelGGL(k_rnn, dim3(64), dim3(512), 0, stream,
                       W_rec, noise, rnn, ex);

    // output = rnn @ W_out^T + b_out
    hipLaunchKernelGGL(k_gemm_nt_bias, dim3((T * NB) / 64, NO / 64), dim3(256), 0, stream,
                       rnn, W_out, b_out, out, T * NB, NO, NH);
}

// Round 7
// 712.521 us; speedup vs baseline: 5.7995x; 5.7995x over previous
//
#include <hip/hip_runtime.h>

// Problem dims (fixed)
constexpr int T  = 512;
constexpr int NB = 64;    // batch
constexpr int NI = 128;   // input
constexpr int NH = 512;   // hidden
constexpr int NO = 64;    // output

constexpr float ALPHA = 0.2f;
constexpr float NSC   = 0.063245553203367586f; // 0.1*sqrt(2*ALPHA)

// ---------------------------------------------------------------------------
// Generic fp32 GEMM: C[M,N] = A[M,K] @ B[N,K]^T + bias[N]   (R3-proven)
__global__ __launch_bounds__(256) void k_gemm_nt_bias(
    const float* __restrict__ A, const float* __restrict__ Bm,
    const float* __restrict__ bias, float* __restrict__ C,
    int M, int N, int K)
{
    __shared__ __align__(16) float As[32][68];
    __shared__ __align__(16) float Bs[32][68];
    const int tid = threadIdx.x;
    const int tx = tid & 15, ty = tid >> 4;
    const long row0 = (long)blockIdx.x * 64;
    const long col0 = (long)blockIdx.y * 64;
    const int lr = tid >> 3;
    const int lq = tid & 7;

    float acc[4][4] = {};

    for (int kt = 0; kt < K; kt += 32) {
        #pragma unroll
        for (int hh = 0; hh < 2; ++hh) {
            const int r = lr + hh * 32;
            const float4 va = *(const float4*)&A[(size_t)(row0 + r) * K + kt + lq * 4];
            As[lq*4+0][r] = va.x; As[lq*4+1][r] = va.y;
            As[lq*4+2][r] = va.z; As[lq*4+3][r] = va.w;
            const float4 vb = *(const float4*)&Bm[(size_t)(col0 + r) * K + kt + lq * 4];
            Bs[lq*4+0][r] = vb.x; Bs[lq*4+1][r] = vb.y;
            Bs[lq*4+2][r] = vb.z; Bs[lq*4+3][r] = vb.w;
        }
        __syncthreads();
        #pragma unroll
        for (int kk = 0; kk < 32; ++kk) {
            const float4 a4 = *(const float4*)&As[kk][ty * 4];
            const float4 b4 = *(const float4*)&Bs[kk][tx * 4];
            const float a[4] = {a4.x, a4.y, a4.z, a4.w};
            const float b[4] = {b4.x, b4.y, b4.z, b4.w};
            #pragma unroll
            for (int i = 0; i < 4; ++i)
                #pragma unroll
                for (int j = 0; j < 4; ++j)
                    acc[i][j] += a[i] * b[j];
        }
        __syncthreads();
    }

    #pragma unroll
    for (int i = 0; i < 4; ++i) {
        const long r = row0 + ty * 4 + i;
        const int  cc = (int)col0 + tx * 4;
        float4 ov;
        ov.x = acc[i][0] + bias[cc + 0];
        ov.y = acc[i][1] + bias[cc + 1];
        ov.z = acc[i][2] + bias[cc + 2];
        ov.w = acc[i][3] + bias[cc + 3];
        *(float4*)&C[(size_t)r * N + cc] = ov;
    }
}

// ---------------------------------------------------------------------------
// u32 exchange word (R3-PROVEN): [31:16]=bf16(h), [15:0]=tag.
// atomic exchange to publish, atomic fetch_or(0) to poll — RELAXED+AGENT
// RMWs execute at the device coherence point (cross-XCD-safe, no cache
// maintenance in the loop).
__device__ __forceinline__ uint32_t pack_h(float h, uint32_t tag) {
    uint32_t u = __float_as_uint(h);
    uint32_t r = (u + 0x7FFFu + ((u >> 16) & 1u)) & 0xFFFF0000u;  // RNE to bf16
    return r | (tag & 0xFFFFu);
}

// ---------------------------------------------------------------------------
// Recurrent kernel, R3 structure + LDS-broadcast fix.
//  256 WGs = 64 groups (1 batch) x 4 members; member m owns cols
//  [128m,128m+128); bid = m*64+g.
// DOT remap: wave w (0..7) owns k-chunk [64w,64w+64); lane l computes cols
//  {l, l+64}. h lives in LDS as BF16 (1 KB): per thread 8 wave-uniform
//  ds_read_b128 (8 bf16 each) -> 64 b128/CU/step (was 256 fp32 b128 in R3).
//  W fp32 register-resident: 2 cols x 64 k = 128 VGPR. h_old (fp32) carried
//  in epilogue-thread registers, NOT in LDS.
// Sync identical to R3: per step, tid<128 epilogue+publish; tid>=128 poll
//  one peer word each; 2-slot parity t&1, tag t+1; overwrite-safety chain
//  publish(t+2) <- gather(t+1) <- publish(t+1) <- barrier(t) <- gather(t).
// Hang-proofing (R5-proven): launch-global spin budget + sticky alive.
__global__ __launch_bounds__(512, 2) void k_rnn(
    const float* __restrict__ W_rec,   // [H][H]
    const float* __restrict__ noise,   // [T][B][H]
    float* __restrict__ rnn,           // [T][B][H]: xin+b_rec in, h out
    uint32_t* __restrict__ ex)         // [2][B][H] tagged words
{
    const int bid = blockIdx.x;
    const int g = bid & 63;        // group == batch
    const int m = bid >> 6;        // member 0..3
    const int tid = threadIdx.x;
    const int w = tid >> 6;        // wave = k-chunk (64 k wide)
    const int l = tid & 63;        // lane -> cols {l, l+64} of slice

    __shared__ __align__(16) unsigned short hbf[NH];  // bf16 h (1 KB)
    __shared__ __align__(16) float pr[8][128];        // per-chunk partials

    // ---- W rows fp32 into registers (one-time) ----
    float4 w0[16], w1[16];
    {
        const float* p0 = W_rec + (size_t)(m * 128 + l) * NH + w * 64;
        const float* p1 = W_rec + (size_t)(m * 128 + l + 64) * NH + w * 64;
        #pragma unroll
        for (int i = 0; i < 16; ++i) {
            w0[i] = *(const float4*)(p0 + i * 4);
            w1[i] = *(const float4*)(p1 + i * 4);
        }
    }

    const int gc = m * 128 + tid;            // epilogue col (tid<128)

    // poller mapping (tid>=128): one u32 word of one peer
    const int q    = tid - 128;              // 0..383
    const int pp   = q >> 7;                 // 0..2
    const int pm   = pp + (pp >= m ? 1 : 0); // peer member
    const int pcol = pm * 128 + (q & 127);

    // zero bf16 h
    hbf[tid] = 0;

    // fp32 h_old carried in registers (epilogue threads only)
    float hreg = 0.f;

    // prefetch t=0 xin(+b_rec)/noise
    float xin_pf = 0.f, noi_pf = 0.f;
    if (tid < 128) {
        xin_pf = rnn[(size_t)g * NH + gc];
        noi_pf = noise[(size_t)g * NH + gc];
    }
    __syncthreads();

    int alive  = 1;
    int budget = 1 << 16;   // launch-global spin budget (hang-proof)

    for (int t = 0; t < T; ++t) {
        // ---- dot: cols {l, l+64}, k in [64w, 64w+64), h from bf16 LDS ----
        float a0 = 0.f, a1 = 0.f, a2 = 0.f, a3 = 0.f;   // col l accum (split)
        float b0 = 0.f, b1 = 0.f, b2 = 0.f, b3 = 0.f;   // col l+64 accum
        {
            const uint4* hp = (const uint4*)&hbf[w * 64];  // 8 x (8 bf16)
            #pragma unroll
            for (int i = 0; i < 8; ++i) {
                const uint4 u = hp[i];                     // broadcast b128
                const float h0 = __uint_as_float(u.x << 16);
                const float h1 = __uint_as_float(u.x & 0xFFFF0000u);
                const float h2 = __uint_as_float(u.y << 16);
                const float h3 = __uint_as_float(u.y & 0xFFFF0000u);
                const float h4 = __uint_as_float(u.z << 16);
                const float h5 = __uint_as_float(u.z & 0xFFFF0000u);
                const float h6 = __uint_as_float(u.w << 16);
                const float h7 = __uint_as_float(u.w & 0xFFFF0000u);
                const float4 wa0 = w0[i * 2], wa1 = w0[i * 2 + 1];
                const float4 wb0 = w1[i * 2], wb1 = w1[i * 2 + 1];
                a0 += wa0.x * h0;  a1 += wa0.y * h1;
                a2 += wa0.z * h2;  a3 += wa0.w * h3;
                a0 += wa1.x * h4;  a1 += wa1.y * h5;
                a2 += wa1.z * h6;  a3 += wa1.w * h7;
                b0 += wb0.x * h0;  b1 += wb0.y * h1;
                b2 += wb0.z * h2;  b3 += wb0.w * h3;
                b0 += wb1.x * h4;  b1 += wb1.y * h5;
                b2 += wb1.z * h6;  b3 += wb1.w * h7;
            }
        }
        pr[w][l]      = (a0 + a1) + (a2 + a3);
        pr[w][l + 64] = (b0 + b1) + (b2 + b3);
        __syncthreads();

        const uint32_t want = (uint32_t)(t + 1);
        uint32_t* slot = ex + (size_t)(t & 1) * NB * NH;

        if (tid < 128) {
            // ---- epilogue: reduce 8 chunk-partials, update, publish ----
            float sum = 0.f;
            #pragma unroll
            for (int k = 0; k < 8; ++k) sum += pr[k][tid];
            const float hn = fmaxf(xin_pf + sum, 0.f);     // b_rec folded in xin
            const float nw = (1.f - ALPHA) * hreg + ALPHA * hn + NSC * noi_pf;
            hreg = nw;
            const uint32_t pk = pack_h(nw, want);
            (void)__hip_atomic_exchange(&slot[(size_t)g * NH + gc], pk,
                                        __ATOMIC_RELAXED, __HIP_MEMORY_SCOPE_AGENT);
            hbf[gc] = (unsigned short)(pk >> 16);          // own col, same rounding
            rnn[((size_t)t * NB + g) * NH + gc] = nw;
            const int tn = (t + 1 < T) ? (t + 1) : t;
            xin_pf = rnn[((size_t)tn * NB + g) * NH + gc];
            noi_pf = noise[((size_t)tn * NB + g) * NH + gc];
        } else {
            // ---- gather: poll one peer word via RMW ----
            uint32_t v;
            if (alive) {
                for (;;) {
                    v = __hip_atomic_fetch_or(&slot[(size_t)g * NH + pcol], 0u,
                                              __ATOMIC_RELAXED, __HIP_MEMORY_SCOPE_AGENT);
                    if ((v & 0xFFFFu) == (want & 0xFFFFu)) break;
                    __builtin_amdgcn_s_sleep(1);
                    if (--budget < 0) { alive = 0; break; }   // fail loudly
                }
            } else {
                v = __hip_atomic_fetch_or(&slot[(size_t)g * NH + pcol], 0u,
                                          __ATOMIC_RELAXED, __HIP_MEMORY_SCOPE_AGENT);
            }
            hbf[pcol] = (unsigned short)(v >> 16);
        }
        __syncthreads();
    }
}

// ---------------------------------------------------------------------------
extern "C" void kernel_launch(void* const* d_in, const int* in_sizes, int n_in,
                              void* d_out, int out_size, void* d_ws, size_t ws_size,
                              hipStream_t stream)
{
    (void)in_sizes; (void)n_in; (void)out_size; (void)ws_size;
    const float* x     = (const float*)d_in[0];
    const float* noise = (const float*)d_in[1];
    const float* W_in  = (const float*)d_in[2];
    const float* W_rec = (const float*)d_in[3];
    const float* b_rec = (const float*)d_in[4];
    const float* W_out = (const float*)d_in[5];
    const float* b_out = (const float*)d_in[6];

    float* out = (float*)d_out;                       // [T*B][O]
    float* rnn = out + (size_t)T * NB * NO;           // [T*B][H] (second output)

    uint32_t* ex = (uint32_t*)d_ws;                   // [2][B][H] = 256 KB

    // clear exchange tags (replay-deterministic; tag 0 never polled-for)
    hipMemsetAsync(ex, 0, (size_t)2 * NB * NH * sizeof(uint32_t), stream);

    // xin = x @ W_in^T + b_rec  -> written into rnn region (in-place consumed)
    hipLaunchKernelGGL(k_gemm_nt_bias, dim3((T * NB) / 64, NH / 64), dim3(256), 0, stream,
                       x, W_in, b_rec, rnn, T * NB, NH, NI);

    // sequential recurrence: 256 WGs, bf16-LDS dot, u32 RMW sync (R3 semantics)
    hipLaunchKernelGGL(k_rnn, dim3(256), dim3(512), 0, stream,
                       W_rec, noise, rnn, ex);

    // output = rnn @ W_out^T + b_out
    hipLaunchKernelGGL(k_gemm_nt_bias, dim3((T * NB) / 64, NO / 64), dim3(256), 0, stream,
                       rnn, W_out, b_out, out, T * NB, NO, NH);
}